// Round 3
// baseline (126.219 us; speedup 1.0000x reference)
//
#include <hip/hip_runtime.h>
#include <cstdint>
#include <cstddef>

// Problem constants
#define FF 64
#define EE 64
#define HH 8
#define PP 512
#define MM 16384   // B*T = 64*256
#define KK 1024    // 2 * F * H  (both branches concatenated)

typedef __bf16 bf16x8 __attribute__((ext_vector_type(8)));
typedef float  floatx4 __attribute__((ext_vector_type(4)));

// float -> bf16 (RNE)
__device__ __forceinline__ unsigned short f2bf(float f) {
    unsigned int u = __float_as_uint(f);
    u += 0x7FFFu + ((u >> 16) & 1u);
    return (unsigned short)(u >> 16);
}

__device__ __forceinline__ unsigned pack2(unsigned short a, unsigned short b) {
    return (unsigned)a | ((unsigned)b << 16);
}

// tanh from pre-scaled arg t = (val*w+b)*2*log2e:  1 - 2/(exp2(t)+1)
// (the 2*log2e factor is folded into the LDS-staged w1/b1)
__device__ __forceinline__ float fast_tanh_s(float t) {
    float e, r;
    asm("v_exp_f32 %0, %1" : "=v"(e) : "v"(t));
    float d = e + 1.0f;
    asm("v_rcp_f32 %0, %1" : "=v"(r) : "v"(d));
    return __builtin_fmaf(-2.0f, r, 1.0f);
}

// async global->LDS, 16B per lane; LDS dest = wave-uniform base + lane*16
__device__ __forceinline__ void gl_lds16(const unsigned short* g, unsigned short* s) {
    __builtin_amdgcn_global_load_lds(
        (__attribute__((address_space(1))) void*)(void*)g,
        (__attribute__((address_space(3))) void*)s,
        16, 0, 0);
}

// ---------------------------------------------------------------------------
// Phase 1: BmatT[n][k] (bf16, k-contiguous), k = br*512 + f*8 + h
//   BmatT[n][br,f,h] = sum_e w2[f,h,e] * W[(f*64+e)*512 + n]
// (unchanged — verified at 125.3 us baseline)
// ---------------------------------------------------------------------------
__global__ __launch_bounds__(256) void combine_kernel(
    const float* __restrict__ w2v, const float* __restrict__ w2t,
    const float* __restrict__ wx,  const float* __restrict__ wt,
    unsigned short* __restrict__ BmatT)
{
    const int tid = threadIdx.x;
    const int bid = blockIdx.x;
    const int br = bid >> 7;
    const int f  = (bid >> 1) & 63;
    const int nh = bid & 1;
    const float* __restrict__ w2 = br ? w2t : w2v;   // [F][H][E]
    const float* __restrict__ W  = br ? wt  : wx;    // [F*E][P]
    __shared__ float w2s[HH * EE];
    for (int i = tid; i < HH * EE; i += 256) w2s[i] = w2[f * HH * EE + i];
    __syncthreads();
    const int n = nh * 256 + tid;
    float acc[HH] = {0,0,0,0,0,0,0,0};
    const float* Wcol = W + (size_t)f * EE * PP + n;
    #pragma unroll 8
    for (int e = 0; e < EE; ++e) {
        const float wv = Wcol[(size_t)e * PP];
        #pragma unroll
        for (int h = 0; h < HH; ++h)
            acc[h] = __builtin_fmaf(w2s[h * EE + e], wv, acc[h]);
    }
    uint4 v;
    v.x = pack2(f2bf(acc[0]), f2bf(acc[1]));
    v.y = pack2(f2bf(acc[2]), f2bf(acc[3]));
    v.z = pack2(f2bf(acc[4]), f2bf(acc[5]));
    v.w = pack2(f2bf(acc[6]), f2bf(acc[7]));
    *reinterpret_cast<uint4*>(&BmatT[(size_t)n * KK + br * 512 + f * 8]) = v;
}

// ---------------------------------------------------------------------------
// Phase 2: fused featurize + GEMM.
//   out[m][n] = sum_k A[m][k]*BmatT[n][k] + bx[n] + bt[n]
//   A[m][br*512+f*8+h] = tanh(in_br[m][f]*w1[f][h]+b1[f][h])  in-tile.
//
// Round-3 change (single lever vs round-0 structure): 4 waves (256 threads)
// instead of 8, wave tile 64x64 (acc 4x4) instead of 32x64 (acc 2x4).
//   - Frag-read LDS traffic per block-iter: 96KB -> 64KB (-33%); total LDS
//     per block-iter 1088 -> 832 bank-cycles (-24%). Theory: gemm is
//     LDS-array-BW-bound (round-2 showed it is NOT load-latency-bound).
//   - KEEPS 2 independent blocks/CU (LDS 48KB, grid 512) — the async
//     cross-block phase overlap round-1 proved essential. 8 waves/CU,
//     2/SIMD, one from each block; per-wave ILP doubles (32 indep MFMAs).
//   - VGPR: acc 64 + frags 32 + misc ~ <128, cap 256 at 2 waves/SIMD.
//   - Same XOR swizzles on As/Bs writes+reads (verified conflict-free).
//   - Same grid (256,2): ids x, x+256 same XCD -> x/time L2 reuse.
// ---------------------------------------------------------------------------
__global__ __launch_bounds__(256, 2) void gemm_fused_kernel(
    const float* __restrict__ x,   const float* __restrict__ tmv,
    const float* __restrict__ w1v, const float* __restrict__ b1v,
    const float* __restrict__ w1t, const float* __restrict__ b1t,
    const unsigned short* __restrict__ Bt,  // BmatT [PP][KK]
    const float* __restrict__ bx, const float* __restrict__ bt,
    float* __restrict__ out)                 // [MM][PP]
{
    __shared__ __align__(16) unsigned short As[64 * 64];    // 8 KB
    __shared__ __align__(16) unsigned short Bs[256 * 64];   // 32 KB
    __shared__ __align__(16) float w1s[2 * FF * HH];        // 4 KB (pre-scaled)
    __shared__ __align__(16) float b1s[2 * FF * HH];        // 4 KB (pre-scaled)

    const int tid  = threadIdx.x;
    const int wave = tid >> 6;             // 0..3
    const int lane = tid & 63;
    const int m0 = blockIdx.x * 64;
    const int n0 = blockIdx.y * 256;

    // stage w1/b1 scaled by 2*log2e (folds the mul out of every tanh)
    {
        const float c = 2.8853900817779268f;
        #pragma unroll
        for (int t = 0; t < 4; ++t) {
            const int idx = tid + t * 256;
            const int br  = idx >> 9;
            const int rem = idx & 511;
            w1s[idx] = (br ? w1t : w1v)[rem] * c;
            b1s[idx] = (br ? b1t : b1v)[rem] * c;
        }
    }
    __syncthreads();

    const int wn  = wave;                  // 0..3  (n quadrant, 64 cols)
    const int q   = lane >> 4;
    const int ml  = lane & 15;
    const int mlx = ml & 7;
    const int lr  = lane >> 3;             // 0..7 row within 8-row segment
    const int lkg = ((lane & 7) ^ lr) * 8; // swizzled global k-offset (shorts)
    const int fi  = tid & 7;               // feature sub-index for A-compute
    const int arow = tid >> 3;             // 0..31: A rows arow, arow+32
    const int pchunk = (fi ^ (arow & 7)) * 8;   // same for arow+32 (bit5 untouched)

    floatx4 acc[4][4];
    #pragma unroll
    for (int i = 0; i < 4; ++i)
        #pragma unroll
        for (int j = 0; j < 4; ++j)
            acc[i][j] = (floatx4){0.f, 0.f, 0.f, 0.f};

    // software-pipelined input values (two rows share one w1/b1 read)
    float vcur0 = x[(size_t)(m0 + arow) * FF + fi];
    float vcur1 = x[(size_t)(m0 + arow + 32) * FF + fi];
    float vnx0 = 0.f, vnx1 = 0.f;

    for (int i = 0; i < 16; ++i) {
        const int k0 = i * 64;
        const int br = i >> 3;

        // ---- B staging (DMA overlaps the tanh VALU below) ----
        #pragma unroll
        for (int j = 0; j < 8; ++j) {
            const int seg = wave * 8 + j;        // 0..31, 8 rows each
            gl_lds16(&Bt[(size_t)(n0 + seg * 8 + lr) * KK + k0 + lkg], &Bs[seg * 512]);
        }

        // ---- A tile: two (row, f) chunks of 8 tanh per thread ----
        {
            const int f = ((i & 7) << 3) + fi;
            const float4 wlo = reinterpret_cast<const float4*>(w1s)[br * 128 + f * 2];
            const float4 whi = reinterpret_cast<const float4*>(w1s)[br * 128 + f * 2 + 1];
            const float4 blo = reinterpret_cast<const float4*>(b1s)[br * 128 + f * 2];
            const float4 bhi = reinterpret_cast<const float4*>(b1s)[br * 128 + f * 2 + 1];
            float h0[8], h1[8];
            h0[0] = fast_tanh_s(__builtin_fmaf(vcur0, wlo.x, blo.x));
            h0[1] = fast_tanh_s(__builtin_fmaf(vcur0, wlo.y, blo.y));
            h0[2] = fast_tanh_s(__builtin_fmaf(vcur0, wlo.z, blo.z));
            h0[3] = fast_tanh_s(__builtin_fmaf(vcur0, wlo.w, blo.w));
            h0[4] = fast_tanh_s(__builtin_fmaf(vcur0, whi.x, bhi.x));
            h0[5] = fast_tanh_s(__builtin_fmaf(vcur0, whi.y, bhi.y));
            h0[6] = fast_tanh_s(__builtin_fmaf(vcur0, whi.z, bhi.z));
            h0[7] = fast_tanh_s(__builtin_fmaf(vcur0, whi.w, bhi.w));
            h1[0] = fast_tanh_s(__builtin_fmaf(vcur1, wlo.x, blo.x));
            h1[1] = fast_tanh_s(__builtin_fmaf(vcur1, wlo.y, blo.y));
            h1[2] = fast_tanh_s(__builtin_fmaf(vcur1, wlo.z, blo.z));
            h1[3] = fast_tanh_s(__builtin_fmaf(vcur1, wlo.w, blo.w));
            h1[4] = fast_tanh_s(__builtin_fmaf(vcur1, whi.x, bhi.x));
            h1[5] = fast_tanh_s(__builtin_fmaf(vcur1, whi.y, bhi.y));
            h1[6] = fast_tanh_s(__builtin_fmaf(vcur1, whi.z, bhi.z));
            h1[7] = fast_tanh_s(__builtin_fmaf(vcur1, whi.w, bhi.w));
            uint4 v;
            v.x = pack2(f2bf(h0[0]), f2bf(h0[1]));
            v.y = pack2(f2bf(h0[2]), f2bf(h0[3]));
            v.z = pack2(f2bf(h0[4]), f2bf(h0[5]));
            v.w = pack2(f2bf(h0[6]), f2bf(h0[7]));
            *reinterpret_cast<uint4*>(&As[arow * 64 + pchunk]) = v;
            v.x = pack2(f2bf(h1[0]), f2bf(h1[1]));
            v.y = pack2(f2bf(h1[2]), f2bf(h1[3]));
            v.z = pack2(f2bf(h1[4]), f2bf(h1[5]));
            v.w = pack2(f2bf(h1[6]), f2bf(h1[7]));
            *reinterpret_cast<uint4*>(&As[(arow + 32) * 64 + pchunk]) = v;
        }
        __syncthreads();   // As writes + Bs DMA visible

        // ---- prefetch next iter's input values (hide under MFMA below) ----
        if (i < 15) {
            const int in = i + 1;
            const float* __restrict__ inp = (in & 8) ? tmv : x;
            const int fn = ((in & 7) << 3) + fi;
            vnx0 = inp[(size_t)(m0 + arow) * FF + fn];
            vnx1 = inp[(size_t)(m0 + arow + 32) * FF + fn];
        }

        #pragma unroll
        for (int kk = 0; kk < 64; kk += 32) {
            const int cl = (kk >> 3) + q;          // logical chunk 0..7
            const int co = (cl ^ mlx) * 8;          // swizzled offset (shorts)
            bf16x8 af[4], bfr[4];
            #pragma unroll
            for (int mt = 0; mt < 4; ++mt)
                af[mt] = *reinterpret_cast<const bf16x8*>(
                    &As[(mt * 16 + ml) * 64 + co]);
            #pragma unroll
            for (int nt = 0; nt < 4; ++nt)
                bfr[nt] = *reinterpret_cast<const bf16x8*>(
                    &Bs[(wn * 64 + nt * 16 + ml) * 64 + co]);
            #pragma unroll
            for (int mt = 0; mt < 4; ++mt)
                #pragma unroll
                for (int nt = 0; nt < 4; ++nt)
                    acc[mt][nt] = __builtin_amdgcn_mfma_f32_16x16x32_bf16(
                        af[mt], bfr[nt], acc[mt][nt], 0, 0, 0);
        }
        __syncthreads();   // before next iteration overwrites LDS

        vcur0 = vnx0;
        vcur1 = vnx1;
    }

    // epilogue: nt innermost -> 4 consecutive 64B chunks per output row
    float bias[4];
    #pragma unroll
    for (int nt = 0; nt < 4; ++nt) {
        const int n = n0 + wn * 64 + nt * 16 + ml;
        bias[nt] = bx[n] + bt[n];
    }
    #pragma unroll
    for (int mt = 0; mt < 4; ++mt) {
        const int mb = m0 + mt * 16 + q * 4;
        #pragma unroll
        for (int r = 0; r < 4; ++r) {
            float* orow = out + (size_t)(mb + r) * PP + n0 + wn * 64 + ml;
            #pragma unroll
            for (int nt = 0; nt < 4; ++nt)
                orow[nt * 16] = acc[mt][nt][r] + bias[nt];
        }
    }
}

// ---------------------------------------------------------------------------
extern "C" void kernel_launch(void* const* d_in, const int* in_sizes, int n_in,
                              void* d_out, int out_size, void* d_ws, size_t ws_size,
                              hipStream_t stream)
{
    const float* x   = (const float*)d_in[0];
    const float* tmv = (const float*)d_in[1];
    const float* w1v = (const float*)d_in[2];
    const float* b1v = (const float*)d_in[3];
    const float* w2v = (const float*)d_in[4];
    const float* w1t = (const float*)d_in[5];
    const float* b1t = (const float*)d_in[6];
    const float* w2t = (const float*)d_in[7];
    const float* wx  = (const float*)d_in[8];
    const float* bx  = (const float*)d_in[9];
    const float* wt  = (const float*)d_in[10];
    const float* bt  = (const float*)d_in[11];
    float* out = (float*)d_out;

    // ws: [0,1MB) BmatT bf16 [512][1024]
    unsigned short* Bws = (unsigned short*)d_ws;

    combine_kernel<<<256, 256, 0, stream>>>(w2v, w2t, wx, wt, Bws);
    gemm_fused_kernel<<<dim3(MM / 64, PP / 256), 256, 0, stream>>>(
        x, tmv, w1v, b1v, w1t, b1t, Bws, bx, bt, out);
}